// Round 2
// baseline (208.596 us; speedup 1.0000x reference)
//
#include <hip/hip_runtime.h>

#define WW 512
#define HH 512
#define NPLANES 64   // B*C = 16*4
#define NCH 4
#define NSTRIP 8     // 64-row strips per plane (4 waves x 16 rows per block)

// sigmoid((x - 0.5) * 10) = 1 / (1 + exp2(-x*10*log2e + 5*log2e))
// one fma + v_exp_f32 + add + v_rcp_f32
__device__ __forceinline__ float sigf(float x) {
    float e = __builtin_amdgcn_exp2f(__builtin_fmaf(x, -14.4269504089f, 7.2134752044f));
    return __builtin_amdgcn_rcpf(1.0f + e);
}

__device__ __forceinline__ void load_sig_row(const float* __restrict__ p, float* o) {
    const float4* p4 = reinterpret_cast<const float4*>(p);
    float4 a = p4[0];
    float4 b = p4[1];
    o[0] = sigf(a.x); o[1] = sigf(a.y); o[2] = sigf(a.z); o[3] = sigf(a.w);
    o[4] = sigf(b.x); o[5] = sigf(b.y); o[6] = sigf(b.z); o[7] = sigf(b.w);
}

// Stage 1: per plane (b,c) and per tensor (input/target):
//   colpart[tensor][plane][strip][c]  (column partial sums, strip-local)
//   rowsum[tensor][plane][r]          (full row sums of horizontal bounds)
// Grid: 2 tensors * 64 planes * 8 strips = 1024 blocks, 256 threads.
// Each wave handles 16 rows, full width; lane owns 8 contiguous columns.
__global__ __launch_bounds__(256, 8)
void k_stage1(const float* __restrict__ inp, const float* __restrict__ tgt,
              float* __restrict__ colpart, float* __restrict__ rowsum,
              float* __restrict__ out) {
    const int bid    = blockIdx.x;
    const int tensor = bid >> 9;          // 0..1
    const int plane  = (bid >> 3) & 63;   // 0..63
    const int s      = bid & 7;           // 0..7 (64-row strip)
    const int tid    = threadIdx.x;
    const int wave   = tid >> 6;
    const int lane   = tid & 63;

    if (bid == 0 && tid == 0) out[0] = 0.0f;  // zero-init for stage-2 atomics

    const float* __restrict__ base =
        (tensor == 0 ? inp : tgt) + (size_t)plane * (HH * WW);
    const int r0    = s * 64 + wave * 16;
    const int cbase = lane * 8;

    float prev[8], cur[8], nxt[8], cacc[8];
    #pragma unroll
    for (int k = 0; k < 8; ++k) cacc[k] = 0.0f;

    if (r0 == 0) {
        #pragma unroll
        for (int k = 0; k < 8; ++k) prev[k] = 0.0f;  // zero-pad row -1 (of x_sig)
    } else {
        load_sig_row(base + (size_t)(r0 - 1) * WW + cbase, prev);
    }
    load_sig_row(base + (size_t)r0 * WW + cbase, cur);

    float* __restrict__ rs_out = rowsum + ((size_t)tensor * NPLANES + plane) * HH;

    #pragma unroll
    for (int rr = 0; rr < 16; ++rr) {
        const int r = r0 + rr;
        if (r + 1 < HH) {
            load_sig_row(base + (size_t)(r + 1) * WW + cbase, nxt);
        } else {
            #pragma unroll
            for (int k = 0; k < 8; ++k) nxt[k] = 0.0f;  // zero-pad row H
        }

        // vertical bounds -> column sums (per-lane, no comms)
        #pragma unroll
        for (int k = 0; k < 8; ++k)
            cacc[k] += sigf(fabsf(nxt[k] - prev[k]));

        // horizontal bounds on row r: +-1 column (cross-lane at chunk edges)
        float lv = __shfl_up(cur[7], 1);
        if (lane == 0)  lv = 0.0f;   // zero-pad col -1
        float rv = __shfl_down(cur[0], 1);
        if (lane == 63) rv = 0.0f;   // zero-pad col W

        float hp = sigf(fabsf(cur[1] - lv));
        #pragma unroll
        for (int k = 1; k < 7; ++k)
            hp += sigf(fabsf(cur[k + 1] - cur[k - 1]));
        hp += sigf(fabsf(rv - cur[6]));

        // wave reduce (64 lanes)
        #pragma unroll
        for (int off = 32; off >= 1; off >>= 1)
            hp += __shfl_xor(hp, off);
        if (lane == 0) rs_out[r] = hp;

        // rotate rolling window
        #pragma unroll
        for (int k = 0; k < 8; ++k) { prev[k] = cur[k]; cur[k] = nxt[k]; }
    }

    // combine column partials across the 4 waves of this block
    __shared__ float cl[4][WW];
    #pragma unroll
    for (int k = 0; k < 8; ++k) cl[wave][cbase + k] = cacc[k];
    __syncthreads();

    float* __restrict__ cp_out =
        colpart + (((size_t)tensor * NPLANES + plane) * NSTRIP + s) * WW;
    for (int c = tid; c < WW; c += 256)
        cp_out[c] = cl[0][c] + cl[1][c] + cl[2][c] + cl[3][c];
}

// logical sobel-source value: S(0)=512*sig(0), S(j)=sum[j-1], 0 outside [0,512)
__device__ __forceinline__ float Sval(const float* s, int j, float s0) {
    if (j < 0 || j >= 512) return 0.0f;
    if (j == 0) return s0;
    return s[j - 1];
}
__device__ __forceinline__ float term(const float* s, int j, float s0) {
    return fabsf(Sval(s, j + 1, s0) - Sval(s, j - 1, s0));
}

// Stage 2 (merged with mean): one block per plane; finalize colsums,
// sobel+abs+sum both directions for both tensors, atomicAdd mean contribution.
__global__ __launch_bounds__(256)
void k_stage2(const float* __restrict__ colpart, const float* __restrict__ rowsum,
              const float* __restrict__ weight, float* __restrict__ out) {
    __shared__ float cI[WW], cT[WW], rI[WW], rT[WW];
    const int p   = blockIdx.x;   // plane = b*4 + c
    const int tid = threadIdx.x;

    for (int c = tid; c < WW; c += 256) {
        const float* a = colpart + (((size_t)0 * NPLANES + p) * NSTRIP) * WW + c;
        const float* b = colpart + (((size_t)1 * NPLANES + p) * NSTRIP) * WW + c;
        float sa = 0.f, sb = 0.f;
        #pragma unroll
        for (int i = 0; i < NSTRIP; ++i) { sa += a[i * WW]; sb += b[i * WW]; }
        cI[c] = sa;
        cT[c] = sb;
        rI[c] = rowsum[((size_t)0 * NPLANES + p) * HH + c];
        rT[c] = rowsum[((size_t)1 * NPLANES + p) * HH + c];
    }
    __syncthreads();

    // 512 * sigmoid(-5)
    const float s0 = 3.4267396732f;

    float sIx = 0.f, sTx = 0.f, sIy = 0.f, sTy = 0.f;
    for (int j = tid; j < WW; j += 256) {
        sIx += term(cI, j, s0);
        sTx += term(cT, j, s0);
        sIy += term(rI, j, s0);
        sTy += term(rT, j, s0);
    }
    #pragma unroll
    for (int off = 32; off >= 1; off >>= 1) {
        sIx += __shfl_xor(sIx, off);
        sTx += __shfl_xor(sTx, off);
        sIy += __shfl_xor(sIy, off);
        sTy += __shfl_xor(sTy, off);
    }
    __shared__ float red[4][4];
    const int wave = tid >> 6, lane = tid & 63;
    if (lane == 0) {
        red[wave][0] = sIx; red[wave][1] = sTx;
        red[wave][2] = sIy; red[wave][3] = sTy;
    }
    __syncthreads();
    if (tid == 0) {
        float Ix = 0.f, Tx = 0.f, Iy = 0.f, Ty = 0.f;
        for (int w2 = 0; w2 < 4; ++w2) {
            Ix += red[w2][0]; Tx += red[w2][1];
            Iy += red[w2][2]; Ty += red[w2][3];
        }
        Ix *= 0.25f; Tx *= 0.25f; Iy *= 0.25f; Ty *= 0.25f;
        const float wgt = weight[p & (NCH - 1)];
        float loss = 0.5f * (fabsf((Ix - Tx) * wgt) + fabsf((Iy - Ty) * wgt));
        atomicAdd(out, loss * (1.0f / NPLANES));
    }
}

extern "C" void kernel_launch(void* const* d_in, const int* in_sizes, int n_in,
                              void* d_out, int out_size, void* d_ws, size_t ws_size,
                              hipStream_t stream) {
    const float* inp = (const float*)d_in[0];
    const float* tgt = (const float*)d_in[1];
    const float* wgt = (const float*)d_in[2];
    float* ws = (float*)d_ws;

    // ws layout (floats):
    float* colpart = ws;                       // [2][64][8][512] = 524288
    float* rowsum  = ws + 524288;              // [2][64][512]    = 65536

    k_stage1<<<1024, 256, 0, stream>>>(inp, tgt, colpart, rowsum, (float*)d_out);
    k_stage2<<<64, 256, 0, stream>>>(colpart, rowsum, wgt, (float*)d_out);
}

// Round 3
// 153.451 us; speedup vs baseline: 1.3594x; 1.3594x over previous
//
#include <hip/hip_runtime.h>

#define WW 512
#define HH 512
#define NPLANES 64   // B*C = 16*4
#define NCH 4
#define NSTRIP 8     // 64-row strips per plane (4 waves x 16 rows per block)

// sigmoid((x - 0.5) * 10) = 1 / (1 + exp2(-x*10*log2e + 5*log2e))
// one fma + v_exp_f32 + add + v_rcp_f32
__device__ __forceinline__ float sigf(float x) {
    float e = __builtin_amdgcn_exp2f(__builtin_fmaf(x, -14.4269504089f, 7.2134752044f));
    return __builtin_amdgcn_rcpf(1.0f + e);
}

// Stage 1: per plane (b,c) and per tensor (input/target):
//   colpart[tensor][plane][strip][c]   column partial sums (strip-local)
//   rowsum8[tensor][plane][r][8]       row sums as 8 lane-group partials
// Grid: 2 tensors * 64 planes * 8 strips = 1024 blocks, 256 threads.
// Each wave handles 16 rows, full width; lane owns 8 contiguous columns.
// launch_bounds(256,4): 128-VGPR cap -- (256,8) spilled 134 MB to scratch (R2).
__global__ __launch_bounds__(256, 4)
void k_stage1(const float* __restrict__ inp, const float* __restrict__ tgt,
              float* __restrict__ colpart, float* __restrict__ rowsum8,
              float* __restrict__ out) {
    const int bid    = blockIdx.x;
    const int tensor = bid >> 9;          // 0..1
    const int plane  = (bid >> 3) & 63;   // 0..63
    const int s      = bid & 7;           // 0..7 (64-row strip)
    const int tid    = threadIdx.x;
    const int wave   = tid >> 6;
    const int lane   = tid & 63;

    if (bid == 0 && tid == 0) out[0] = 0.0f;  // zero-init for stage-2 atomics

    const float* __restrict__ base =
        (tensor == 0 ? inp : tgt) + (size_t)plane * (HH * WW);
    const int r0    = s * 64 + wave * 16;
    const int r1    = r0 + 16;
    const int cbase = lane * 8;

    float prev[8], cur[8], cacc[8];
    #pragma unroll
    for (int k = 0; k < 8; ++k) cacc[k] = 0.0f;

    // prologue: prev = sig(row r0-1) (zero-pad), cur = sig(row r0)
    if (r0 == 0) {
        #pragma unroll
        for (int k = 0; k < 8; ++k) prev[k] = 0.0f;
    } else {
        const float4* p4 = reinterpret_cast<const float4*>(base + (size_t)(r0 - 1) * WW + cbase);
        float4 a = p4[0], b = p4[1];
        prev[0]=sigf(a.x); prev[1]=sigf(a.y); prev[2]=sigf(a.z); prev[3]=sigf(a.w);
        prev[4]=sigf(b.x); prev[5]=sigf(b.y); prev[6]=sigf(b.z); prev[7]=sigf(b.w);
    }
    {
        const float4* p4 = reinterpret_cast<const float4*>(base + (size_t)r0 * WW + cbase);
        float4 a = p4[0], b = p4[1];
        cur[0]=sigf(a.x); cur[1]=sigf(a.y); cur[2]=sigf(a.z); cur[3]=sigf(a.w);
        cur[4]=sigf(b.x); cur[5]=sigf(b.y); cur[6]=sigf(b.z); cur[7]=sigf(b.w);
    }

    float* __restrict__ rs_out =
        rowsum8 + ((size_t)tensor * NPLANES + plane) * (HH * 8);

    for (int r = r0; r < r1; ++r) {
        // 1) issue next-row loads FIRST (raw; convert later) -- hide latency
        //    behind the horizontal work on cur, which doesn't depend on them.
        float4 a, b;
        if (r + 1 < HH) {
            const float4* p4 = reinterpret_cast<const float4*>(base + (size_t)(r + 1) * WW + cbase);
            a = p4[0]; b = p4[1];
        } else {
            a = make_float4(0.f,0.f,0.f,0.f); b = a;
        }

        // 2) horizontal bounds on row r (edge vals cross-lane)
        float lv = __shfl_up(cur[7], 1);
        if (lane == 0)  lv = 0.0f;   // zero-pad col -1
        float rv = __shfl_down(cur[0], 1);
        if (lane == 63) rv = 0.0f;   // zero-pad col W

        float hp = sigf(fabsf(cur[1] - lv));
        #pragma unroll
        for (int k = 1; k < 7; ++k)
            hp += sigf(fabsf(cur[k + 1] - cur[k - 1]));
        hp += sigf(fabsf(rv - cur[6]));

        // 3-step butterfly: lane i ends with sum over lanes == i (mod 8);
        // lanes 0..7 hold 8 partials covering the full row.
        hp += __shfl_xor(hp, 8);
        hp += __shfl_xor(hp, 16);
        hp += __shfl_xor(hp, 32);
        if (lane < 8) rs_out[(size_t)r * 8 + lane] = hp;

        // 3) convert loaded row, vertical bounds, rotate window
        float nxt[8];
        if (r + 1 < HH) {
            nxt[0]=sigf(a.x); nxt[1]=sigf(a.y); nxt[2]=sigf(a.z); nxt[3]=sigf(a.w);
            nxt[4]=sigf(b.x); nxt[5]=sigf(b.y); nxt[6]=sigf(b.z); nxt[7]=sigf(b.w);
        } else {
            #pragma unroll
            for (int k = 0; k < 8; ++k) nxt[k] = 0.0f;  // zero-pad row H
        }
        #pragma unroll
        for (int k = 0; k < 8; ++k) {
            cacc[k] += sigf(fabsf(nxt[k] - prev[k]));
            prev[k] = cur[k];
            cur[k]  = nxt[k];
        }
    }

    // combine column partials across the 4 waves of this block
    __shared__ float cl[4][WW];
    #pragma unroll
    for (int k = 0; k < 8; ++k) cl[wave][cbase + k] = cacc[k];
    __syncthreads();

    float* __restrict__ cp_out =
        colpart + (((size_t)tensor * NPLANES + plane) * NSTRIP + s) * WW;
    for (int c = tid; c < WW; c += 256)
        cp_out[c] = cl[0][c] + cl[1][c] + cl[2][c] + cl[3][c];
}

// logical sobel-source value: S(0)=512*sig(0), S(j)=sum[j-1], 0 outside [0,512)
__device__ __forceinline__ float Sval(const float* s, int j, float s0) {
    if (j < 0 || j >= 512) return 0.0f;
    if (j == 0) return s0;
    return s[j - 1];
}
__device__ __forceinline__ float term(const float* s, int j, float s0) {
    return fabsf(Sval(s, j + 1, s0) - Sval(s, j - 1, s0));
}

// Stage 2 (merged with mean): one block per plane; finalize col/row sums,
// sobel+abs+sum both directions for both tensors, atomicAdd mean contribution.
__global__ __launch_bounds__(256)
void k_stage2(const float* __restrict__ colpart, const float* __restrict__ rowsum8,
              const float* __restrict__ weight, float* __restrict__ out) {
    __shared__ float cI[WW], cT[WW], rI[WW], rT[WW];
    const int p   = blockIdx.x;   // plane = b*4 + c
    const int tid = threadIdx.x;

    for (int c = tid; c < WW; c += 256) {
        const float* a = colpart + (((size_t)0 * NPLANES + p) * NSTRIP) * WW + c;
        const float* b = colpart + (((size_t)1 * NPLANES + p) * NSTRIP) * WW + c;
        float sa = 0.f, sb = 0.f;
        #pragma unroll
        for (int i = 0; i < NSTRIP; ++i) { sa += a[i * WW]; sb += b[i * WW]; }
        cI[c] = sa;
        cT[c] = sb;
        const float* ra = rowsum8 + ((size_t)0 * NPLANES + p) * (HH * 8) + (size_t)c * 8;
        const float* rb = rowsum8 + ((size_t)1 * NPLANES + p) * (HH * 8) + (size_t)c * 8;
        float sra = 0.f, srb = 0.f;
        #pragma unroll
        for (int i = 0; i < 8; ++i) { sra += ra[i]; srb += rb[i]; }
        rI[c] = sra;
        rT[c] = srb;
    }
    __syncthreads();

    // 512 * sigmoid(-5)
    const float s0 = 3.4267396732f;

    float sIx = 0.f, sTx = 0.f, sIy = 0.f, sTy = 0.f;
    for (int j = tid; j < WW; j += 256) {
        sIx += term(cI, j, s0);
        sTx += term(cT, j, s0);
        sIy += term(rI, j, s0);
        sTy += term(rT, j, s0);
    }
    #pragma unroll
    for (int off = 32; off >= 1; off >>= 1) {
        sIx += __shfl_xor(sIx, off);
        sTx += __shfl_xor(sTx, off);
        sIy += __shfl_xor(sIy, off);
        sTy += __shfl_xor(sTy, off);
    }
    __shared__ float red[4][4];
    const int wave = tid >> 6, lane = tid & 63;
    if (lane == 0) {
        red[wave][0] = sIx; red[wave][1] = sTx;
        red[wave][2] = sIy; red[wave][3] = sTy;
    }
    __syncthreads();
    if (tid == 0) {
        float Ix = 0.f, Tx = 0.f, Iy = 0.f, Ty = 0.f;
        for (int w2 = 0; w2 < 4; ++w2) {
            Ix += red[w2][0]; Tx += red[w2][1];
            Iy += red[w2][2]; Ty += red[w2][3];
        }
        Ix *= 0.25f; Tx *= 0.25f; Iy *= 0.25f; Ty *= 0.25f;
        const float wgt = weight[p & (NCH - 1)];
        float loss = 0.5f * (fabsf((Ix - Tx) * wgt) + fabsf((Iy - Ty) * wgt));
        atomicAdd(out, loss * (1.0f / NPLANES));
    }
}

extern "C" void kernel_launch(void* const* d_in, const int* in_sizes, int n_in,
                              void* d_out, int out_size, void* d_ws, size_t ws_size,
                              hipStream_t stream) {
    const float* inp = (const float*)d_in[0];
    const float* tgt = (const float*)d_in[1];
    const float* wgt = (const float*)d_in[2];
    float* ws = (float*)d_ws;

    // ws layout (floats):
    float* colpart = ws;                       // [2][64][8][512]  = 524288
    float* rowsum8 = ws + 524288;              // [2][64][512][8]  = 524288

    k_stage1<<<1024, 256, 0, stream>>>(inp, tgt, colpart, rowsum8, (float*)d_out);
    k_stage2<<<64, 256, 0, stream>>>(colpart, rowsum8, wgt, (float*)d_out);
}